// Round 1
// baseline (258.717 us; speedup 1.0000x reference)
//
#include <hip/hip_runtime.h>
#include <hip/hip_bf16.h>
#include <stdint.h>

#define NTOT  8192
#define DIM   512
#define NI    8
#define NWAYS (NTOT / NI)
#define TILE  128
#define BK    64
#define MARGINV 0.3f

typedef __bf16 bf16x8 __attribute__((ext_vector_type(8)));
typedef float  f32x4  __attribute__((ext_vector_type(4)));

// order-preserving float<->uint map (monotonic for all finite floats + inf)
__device__ __forceinline__ unsigned f2o(float f) {
  unsigned u = __float_as_uint(f);
  return (u & 0x80000000u) ? ~u : (u | 0x80000000u);
}
__device__ __forceinline__ float o2f(unsigned u) {
  u = (u & 0x80000000u) ? (u & 0x7fffffffu) : ~u;
  return __uint_as_float(u);
}

__device__ __forceinline__ float wave_sum64(float v) {
#pragma unroll
  for (int s = 32; s; s >>= 1) v += __shfl_xor(v, s, 64);
  return v;
}

// async global->LDS, 16B per lane; LDS dest is wave-uniform base + lane*16
__device__ __forceinline__ void async_ld16(const void* g, void* l) {
  __builtin_amdgcn_global_load_lds(
      (__attribute__((address_space(1))) void*)(uintptr_t)g,
      (__attribute__((address_space(3))) void*)l, 16, 0, 0);
}

// ---------------- prep: row sq-norms + bf16 cast ----------------
__global__ void prep_rows(const float* __restrict__ A, float* __restrict__ sq,
                          __hip_bfloat16* __restrict__ A16) {
  const int i = blockIdx.x;
  const int l = threadIdx.x;
  const float* row = A + (size_t)i * DIM;
  __hip_bfloat16* row16 = A16 + (size_t)i * DIM;
  float s = 0.f;
#pragma unroll
  for (int m = 0; m < DIM / 64; ++m) {
    const float v = row[l + 64 * m];
    s = fmaf(v, v, s);
    row16[l + 64 * m] = __float2bfloat16(v);
  }
  s = wave_sum64(s);
  if (l == 0) sq[i] = s;
}

// ---------------- prep: prototypes (class means) ----------------
__global__ void prep_protos(const float* __restrict__ A, float* __restrict__ psq,
                            __hip_bfloat16* __restrict__ P16) {
  const int c = blockIdx.x;
  const int l = threadIdx.x;
  float s = 0.f;
#pragma unroll
  for (int m = 0; m < DIM / 64; ++m) {
    const int d = l + 64 * m;
    float p = 0.f;
#pragma unroll
    for (int r = 0; r < NI; ++r) p += A[(size_t)(c * NI + r) * DIM + d];
    p *= (1.f / NI);
    P16[(size_t)c * DIM + d] = __float2bfloat16(p);
    s = fmaf(p, p, s);
  }
  s = wave_sum64(s);
  if (l == 0) psq[c] = s;
}

__global__ void init_keys(unsigned long long* __restrict__ a,
                          unsigned long long* __restrict__ b) {
  const int i = blockIdx.x * blockDim.x + threadIdx.x;
  if (i < NTOT) { a[i] = ~0ull; b[i] = ~0ull; }
}

// ---------------- fused GEMM + row-min(+argmin) ----------------
// C[i][j] = dot(A[i], B[j]); v = sqB[j] - 2*C  (row-constant sq_a deferred)
// key = (ordered(v)<<32)|j, atomicMin per row.
template <bool MASK_SAME>
__global__ __launch_bounds__(256) void gemm_min(
    const __hip_bfloat16* __restrict__ A, const __hip_bfloat16* __restrict__ B,
    const float* __restrict__ sqB, unsigned long long* __restrict__ out_key) {
  __shared__ __align__(16) __hip_bfloat16 As[TILE * BK];
  __shared__ __align__(16) __hip_bfloat16 Bs[TILE * BK];
  __shared__ unsigned long long rowkey[TILE][2];

  const int t = threadIdx.x;
  const int lane = t & 63;
  const int wv = t >> 6;
  const int wr = wv >> 1;      // wave row (0..1) -> 64 rows
  const int wc = wv & 1;       // wave col (0..1) -> 64 cols
  const int quad = lane >> 4;
  const int lc = lane & 15;

  const int rowBase = blockIdx.y * TILE;
  const int colBase = blockIdx.x * TILE;

  const int srow = t >> 3;       // staging: row within 32-row chunk
  const int scol = (t & 7) * 8;  // staging: bf16 col offset

  f32x4 acc[4][4] = {};

  for (int kt = 0; kt < DIM; kt += BK) {
    __syncthreads();  // protect LDS from previous iteration's readers
#pragma unroll
    for (int it = 0; it < 4; ++it) {
      async_ld16(A + (size_t)(rowBase + it * 32 + srow) * DIM + kt + scol,
                 (char*)As + it * 4096 + wv * 1024);
      async_ld16(B + (size_t)(colBase + it * 32 + srow) * DIM + kt + scol,
                 (char*)Bs + it * 4096 + wv * 1024);
    }
    __syncthreads();  // compiler drains vmcnt before barrier
#pragma unroll
    for (int kk = 0; kk < BK; kk += 32) {
      bf16x8 af[4], bfr[4];
#pragma unroll
      for (int x = 0; x < 4; ++x) {
        af[x]  = *(const bf16x8*)(As + (wr * 64 + x * 16 + lc) * BK + kk + quad * 8);
        bfr[x] = *(const bf16x8*)(Bs + (wc * 64 + x * 16 + lc) * BK + kk + quad * 8);
      }
#pragma unroll
      for (int x = 0; x < 4; ++x)
#pragma unroll
        for (int y = 0; y < 4; ++y)
          acc[x][y] = __builtin_amdgcn_mfma_f32_16x16x32_bf16(af[x], bfr[y],
                                                              acc[x][y], 0, 0, 0);
    }
  }

  // epilogue: C/D layout col=lane&15, row=quad*4+reg
#pragma unroll
  for (int x = 0; x < 4; ++x) {
    unsigned long long kmin[4] = {~0ull, ~0ull, ~0ull, ~0ull};
#pragma unroll
    for (int y = 0; y < 4; ++y) {
      const int col = colBase + wc * 64 + y * 16 + lc;
      const float sb = sqB[col];
#pragma unroll
      for (int r = 0; r < 4; ++r) {
        float v = fmaf(-2.f, acc[x][y][r], sb);
        if (MASK_SAME) {
          const int row = rowBase + wr * 64 + x * 16 + quad * 4 + r;
          if ((row >> 3) == (col >> 3)) v = __int_as_float(0x7f800000);  // +inf
        }
        const unsigned long long key =
            ((unsigned long long)f2o(v) << 32) | (unsigned)col;
        if (key < kmin[r]) kmin[r] = key;
      }
    }
    // butterfly min across the 16 lanes sharing this quad-row group
#pragma unroll
    for (int r = 0; r < 4; ++r) {
#pragma unroll
      for (int s = 1; s < 16; s <<= 1) {
        const unsigned long long o = __shfl_xor(kmin[r], s, 64);
        if (o < kmin[r]) kmin[r] = o;
      }
    }
    if (lc == 0) {
#pragma unroll
      for (int r = 0; r < 4; ++r)
        rowkey[wr * 64 + x * 16 + quad * 4 + r][wc] = kmin[r];
    }
  }
  __syncthreads();
  if (t < TILE) {
    unsigned long long a = rowkey[t][0];
    const unsigned long long b = rowkey[t][1];
    if (b < a) a = b;
    atomicMin(out_key + rowBase + t, a);
  }
}

// ---------------- exact fp32 hardest-positive ----------------
__global__ void ap_kernel(const float* __restrict__ A, float* __restrict__ dist_ap) {
  const int i = blockIdx.x;
  const int l = threadIdx.x;
  const float* ai = A + (size_t)i * DIM;
  float av[DIM / 64];
#pragma unroll
  for (int m = 0; m < DIM / 64; ++m) av[m] = ai[l + 64 * m];
  const int c0 = (i >> 3) << 3;
  float d2max = 0.f;  // self-distance (0) included, as in reference
#pragma unroll
  for (int j = 0; j < NI; ++j) {
    const float* aj = A + (size_t)(c0 + j) * DIM;
    float s = 0.f;
#pragma unroll
    for (int m = 0; m < DIM / 64; ++m) {
      const float d = av[m] - aj[l + 64 * m];
      s = fmaf(d, d, s);
    }
    s = wave_sum64(s);
    d2max = fmaxf(d2max, s);
  }
  if (l == 0) dist_ap[i] = sqrtf(fmaxf(d2max, 1e-12f));
}

// ---------------- final scalar reductions ----------------
__global__ void finalize_kernel(const float* __restrict__ sq,
                                const float* __restrict__ dist_ap,
                                const unsigned long long* __restrict__ an_key,
                                const unsigned long long* __restrict__ pr_key,
                                float* __restrict__ out) {
  const int tid = threadIdx.x;  // 1024 threads
  float loss = 0.f, sp = 0.f, sn = 0.f, acc = 0.f;
  for (int i = tid; i < NTOT; i += 1024) {
    const float ap = dist_ap[i];
    const float anv = o2f((unsigned)(an_key[i] >> 32));
    const float an = sqrtf(fmaxf(sq[i] + anv, 1e-12f));
    loss += fmaxf(ap - an + MARGINV, 0.f);
    sp += ap;
    sn += an;
    acc += ((unsigned)(pr_key[i] & 0xffffffffu) == (unsigned)(i >> 3)) ? 1.f : 0.f;
  }
  loss = wave_sum64(loss);
  sp = wave_sum64(sp);
  sn = wave_sum64(sn);
  acc = wave_sum64(acc);
  __shared__ float red[16][4];
  const int w = tid >> 6, l = tid & 63;
  if (l == 0) { red[w][0] = loss; red[w][1] = acc; red[w][2] = sp; red[w][3] = sn; }
  __syncthreads();
  if (tid == 0) {
    float L = 0, Ac = 0, P = 0, Nn = 0;
    for (int i = 0; i < 16; ++i) {
      L += red[i][0]; Ac += red[i][1]; P += red[i][2]; Nn += red[i][3];
    }
    out[0] = L / NTOT;   // W = 1.0
    out[1] = Ac / NTOT;
    out[2] = P / NTOT;
    out[3] = Nn / NTOT;
  }
}

extern "C" void kernel_launch(void* const* d_in, const int* in_sizes, int n_in,
                              void* d_out, int out_size, void* d_ws, size_t ws_size,
                              hipStream_t stream) {
  const float* inputs = (const float*)d_in[0];
  float* out = (float*)d_out;
  char* w = (char*)d_ws;
  // ws layout (16B-aligned segments), ~9.7 MB total
  float* sq  = (float*)(w);                                  // 8192 f32
  float* psq = (float*)(w + 32768);                          // 1024 f32
  float* dist_ap = (float*)(w + 36864);                      // 8192 f32
  unsigned long long* an_key = (unsigned long long*)(w + 69632);   // 8192 u64
  unsigned long long* pr_key = (unsigned long long*)(w + 135168);  // 8192 u64
  __hip_bfloat16* A16 = (__hip_bfloat16*)(w + 200704);             // 8192*512 bf16
  __hip_bfloat16* P16 = (__hip_bfloat16*)(w + 200704 + (size_t)NTOT * DIM * 2);

  prep_rows<<<NTOT, 64, 0, stream>>>(inputs, sq, A16);
  prep_protos<<<NWAYS, 64, 0, stream>>>(inputs, psq, P16);
  init_keys<<<(NTOT + 255) / 256, 256, 0, stream>>>(an_key, pr_key);
  gemm_min<true><<<dim3(NTOT / TILE, NTOT / TILE), 256, 0, stream>>>(A16, A16, sq, an_key);
  gemm_min<false><<<dim3(NWAYS / TILE, NTOT / TILE), 256, 0, stream>>>(A16, P16, psq, pr_key);
  ap_kernel<<<NTOT, 64, 0, stream>>>(inputs, dist_ap);
  finalize_kernel<<<1, 1024, 0, stream>>>(sq, dist_ap, an_key, pr_key, out);
}

// Round 2
// 181.002 us; speedup vs baseline: 1.4294x; 1.4294x over previous
//
#include <hip/hip_runtime.h>
#include <hip/hip_bf16.h>
#include <stdint.h>

#define NTOT  8192
#define DIM   512
#define NI    8
#define NWAYS 1024
#define TILE  128
#define BK    64
#define NSYM  2080   /* 64*65/2 upper-triangle tile pairs */
#define MARGINV 0.3f

typedef __bf16 bf16x8 __attribute__((ext_vector_type(8)));
typedef float  f32x4  __attribute__((ext_vector_type(4)));

// order-preserving float<->uint map (monotonic for all finite floats +/- inf)
__device__ __forceinline__ unsigned f2o(float f) {
  unsigned u = __float_as_uint(f);
  return (u & 0x80000000u) ? ~u : (u | 0x80000000u);
}
__device__ __forceinline__ float o2f(unsigned u) {
  u = (u & 0x80000000u) ? (u & 0x7fffffffu) : ~u;
  return __uint_as_float(u);
}

__device__ __forceinline__ float wave_sum64(float v) {
#pragma unroll
  for (int s = 32; s; s >>= 1) v += __shfl_xor(v, s, 64);
  return v;
}

__device__ __forceinline__ void async_ld16(const void* g, void* l) {
  __builtin_amdgcn_global_load_lds(
      (__attribute__((address_space(1))) void*)(uintptr_t)g,
      (__attribute__((address_space(3))) void*)l, 16, 0, 0);
}

// ---- prep: row sq-norms + bf16 cast + key init (b<NTOT) | protos (else) ----
__global__ void prep(const float* __restrict__ A, float* __restrict__ sq,
                     float* __restrict__ psq, __hip_bfloat16* __restrict__ A16,
                     __hip_bfloat16* __restrict__ P16,
                     unsigned long long* __restrict__ an_key,
                     unsigned long long* __restrict__ ap_key,
                     unsigned long long* __restrict__ pr_key) {
  const int b = blockIdx.x;
  const int l = threadIdx.x;
  if (b < NTOT) {
    const float* row = A + (size_t)b * DIM;
    __hip_bfloat16* row16 = A16 + (size_t)b * DIM;
    float s = 0.f;
#pragma unroll
    for (int m = 0; m < DIM / 64; ++m) {
      const float v = row[l + 64 * m];
      s = fmaf(v, v, s);
      row16[l + 64 * m] = __float2bfloat16(v);
    }
    s = wave_sum64(s);
    if (l == 0) {
      sq[b] = s;
      an_key[b] = ~0ull;
      pr_key[b] = ~0ull;
      ap_key[b] = 0ull;
    }
  } else {
    const int c = b - NTOT;
    float s = 0.f;
#pragma unroll
    for (int m = 0; m < DIM / 64; ++m) {
      const int d = l + 64 * m;
      float p = 0.f;
#pragma unroll
      for (int r = 0; r < NI; ++r) p += A[(size_t)(c * NI + r) * DIM + d];
      p *= (1.f / NI);
      P16[(size_t)c * DIM + d] = __float2bfloat16(p);
      s = fmaf(p, p, s);
    }
    s = wave_sum64(s);
    if (l == 0) psq[c] = s;
  }
}

// ---- fused symmetric GEMM + min/argmin/max epilogues ----
// blocks [0,NSYM): upper-triangle (bi<=bj) of the 8192x8192 dist matrix.
//   row-side: an_key[row in bi] <- min over cols in bj of (sq[col]-2dot)
//   col-side (bi<bj): an_key[col in bj] <- min over rows in bi of (sq[row]-2dot)
//   diag (bi==bj): same-class mask + ap_key max
// blocks [NSYM, NSYM+512): inputs x protos -> pr_key argmin.
__global__ __launch_bounds__(256) void gemm_fused(
    const __hip_bfloat16* __restrict__ A, const __hip_bfloat16* __restrict__ P,
    const float* __restrict__ sq, const float* __restrict__ psq,
    unsigned long long* __restrict__ an_key,
    unsigned long long* __restrict__ ap_key,
    unsigned long long* __restrict__ pr_key) {
  __shared__ __align__(16) __hip_bfloat16 As[TILE * BK];
  __shared__ __align__(16) __hip_bfloat16 Bs[TILE * BK];
  __shared__ unsigned long long rowkey[TILE][2];
  __shared__ unsigned long long sidekey[TILE][2];  // col-side min OR diag max

  const int b = blockIdx.x;
  const bool isProto = b >= NSYM;
  int bi, bj;
  const __hip_bfloat16* Bmat;
  const float* sqB;
  if (!isProto) {
    bj = (int)((sqrtf(8.0f * b + 1.0f) - 1.0f) * 0.5f);
    while ((bj + 1) * (bj + 2) / 2 <= b) ++bj;
    while (bj * (bj + 1) / 2 > b) --bj;
    bi = b - bj * (bj + 1) / 2;
    Bmat = A;
    sqB = sq;
  } else {
    const int p = b - NSYM;
    bj = p & 7;
    bi = p >> 3;
    Bmat = P;
    sqB = psq;
  }
  const int rowBase = bi * TILE;
  const int colBase = bj * TILE;
  const bool isDiag = !isProto && (bi == bj);
  const bool colSide = !isProto && (bi != bj);

  const int t = threadIdx.x;
  const int lane = t & 63;
  const int wv = t >> 6;
  const int wr = wv >> 1;
  const int wc = wv & 1;
  const int quad = lane >> 4;
  const int lc = lane & 15;
  const int sw = lc & 7;  // xor-swizzle key for fragment reads (= row&7)

  const int srow = t >> 3;                         // staging row in 32-chunk
  const int ssw = ((t & 7) ^ ((t >> 3) & 7)) * 8;  // swizzled source col (bf16)

  f32x4 acc[4][4] = {};

  for (int kt = 0; kt < DIM; kt += BK) {
    __syncthreads();
#pragma unroll
    for (int it = 0; it < 4; ++it) {
      async_ld16(A + (size_t)(rowBase + it * 32 + srow) * DIM + kt + ssw,
                 (char*)As + it * 4096 + wv * 1024);
      async_ld16(Bmat + (size_t)(colBase + it * 32 + srow) * DIM + kt + ssw,
                 (char*)Bs + it * 4096 + wv * 1024);
    }
    __syncthreads();
#pragma unroll
    for (int kk = 0; kk < BK; kk += 32) {
      bf16x8 af[4], bfr[4];
#pragma unroll
      for (int x = 0; x < 4; ++x) {
        af[x]  = *(const bf16x8*)(As + (wr * 64 + x * 16 + lc) * BK +
                                  (((kk >> 3) + quad) ^ sw) * 8);
        bfr[x] = *(const bf16x8*)(Bs + (wc * 64 + x * 16 + lc) * BK +
                                  (((kk >> 3) + quad) ^ sw) * 8);
      }
#pragma unroll
      for (int x = 0; x < 4; ++x)
#pragma unroll
        for (int y = 0; y < 4; ++y)
          acc[x][y] = __builtin_amdgcn_mfma_f32_16x16x32_bf16(af[x], bfr[y],
                                                              acc[x][y], 0, 0, 0);
    }
  }

  // ---- epilogue. C/D layout: col=lane&15, row=quad*4+reg ----
  float sb[4];
#pragma unroll
  for (int y = 0; y < 4; ++y) sb[y] = sqB[colBase + wc * 64 + y * 16 + lc];

  const float INF = __int_as_float(0x7f800000);

  // row-side min (+ diag max)
#pragma unroll
  for (int x = 0; x < 4; ++x) {
    unsigned long long kmin[4] = {~0ull, ~0ull, ~0ull, ~0ull};
    unsigned long long kmax[4] = {0ull, 0ull, 0ull, 0ull};
#pragma unroll
    for (int y = 0; y < 4; ++y) {
      const int col = colBase + wc * 64 + y * 16 + lc;
#pragma unroll
      for (int r = 0; r < 4; ++r) {
        const float v = fmaf(-2.f, acc[x][y][r], sb[y]);
        if (isDiag) {
          const int row = rowBase + wr * 64 + x * 16 + quad * 4 + r;
          const bool same = (row >> 3) == (col >> 3);
          const unsigned long long kn =
              ((unsigned long long)f2o(same ? INF : v) << 32) | (unsigned)col;
          const unsigned long long kx =
              ((unsigned long long)f2o(same ? v : -INF) << 32) | (unsigned)col;
          if (kn < kmin[r]) kmin[r] = kn;
          if (kx > kmax[r]) kmax[r] = kx;
        } else {
          const unsigned long long kn =
              ((unsigned long long)f2o(v) << 32) | (unsigned)col;
          if (kn < kmin[r]) kmin[r] = kn;
        }
      }
    }
#pragma unroll
    for (int r = 0; r < 4; ++r) {
#pragma unroll
      for (int s = 1; s < 16; s <<= 1) {
        const unsigned long long o = __shfl_xor(kmin[r], s, 64);
        if (o < kmin[r]) kmin[r] = o;
      }
    }
    if (isDiag) {
#pragma unroll
      for (int r = 0; r < 4; ++r) {
#pragma unroll
        for (int s = 1; s < 16; s <<= 1) {
          const unsigned long long o = __shfl_xor(kmax[r], s, 64);
          if (o > kmax[r]) kmax[r] = o;
        }
      }
    }
    if (lc == 0) {
#pragma unroll
      for (int r = 0; r < 4; ++r) {
        rowkey[wr * 64 + x * 16 + quad * 4 + r][wc] = kmin[r];
        if (isDiag) sidekey[wr * 64 + x * 16 + quad * 4 + r][wc] = kmax[r];
      }
    }
  }

  // col-side min (off-diagonal sym blocks): transpose direction
  if (colSide) {
    float sa[4][4];
#pragma unroll
    for (int x = 0; x < 4; ++x)
#pragma unroll
      for (int r = 0; r < 4; ++r)
        sa[x][r] = sq[rowBase + wr * 64 + x * 16 + quad * 4 + r];
#pragma unroll
    for (int y = 0; y < 4; ++y) {
      unsigned long long kc = ~0ull;
#pragma unroll
      for (int x = 0; x < 4; ++x)
#pragma unroll
        for (int r = 0; r < 4; ++r) {
          const int row = rowBase + wr * 64 + x * 16 + quad * 4 + r;
          const float v = fmaf(-2.f, acc[x][y][r], sa[x][r]);
          const unsigned long long k =
              ((unsigned long long)f2o(v) << 32) | (unsigned)row;
          if (k < kc) kc = k;
        }
      // combine the 4 quads holding the same column (lanes differ in bits 4-5)
#pragma unroll
      for (int s = 16; s < 64; s <<= 1) {
        const unsigned long long o = __shfl_xor(kc, s, 64);
        if (o < kc) kc = o;
      }
      if (quad == 0) sidekey[wc * 64 + y * 16 + lc][wr] = kc;
    }
  }

  __syncthreads();
  if (t < TILE) {
    unsigned long long a = rowkey[t][0];
    const unsigned long long c = rowkey[t][1];
    if (c < a) a = c;
    atomicMin((isProto ? pr_key : an_key) + rowBase + t, a);
  } else if (t < 2 * TILE) {
    const int i = t - TILE;
    if (colSide) {
      unsigned long long a = sidekey[i][0];
      const unsigned long long c = sidekey[i][1];
      if (c < a) a = c;
      atomicMin(an_key + colBase + i, a);
    } else if (isDiag) {
      unsigned long long a = sidekey[i][0];
      const unsigned long long c = sidekey[i][1];
      if (c > a) a = c;
      atomicMax(ap_key + rowBase + i, a);
    }
  }
}

// ---- final scalar reductions ----
__global__ void finalize_kernel(const float* __restrict__ sq,
                                const unsigned long long* __restrict__ an_key,
                                const unsigned long long* __restrict__ ap_key,
                                const unsigned long long* __restrict__ pr_key,
                                float* __restrict__ out) {
  const int tid = threadIdx.x;  // 1024 threads
  float loss = 0.f, sp = 0.f, sn = 0.f, acc = 0.f;
  for (int i = tid; i < NTOT; i += 1024) {
    const float s = sq[i];
    const float ap = sqrtf(fmaxf(s + o2f((unsigned)(ap_key[i] >> 32)), 1e-12f));
    const float an = sqrtf(fmaxf(s + o2f((unsigned)(an_key[i] >> 32)), 1e-12f));
    loss += fmaxf(ap - an + MARGINV, 0.f);
    sp += ap;
    sn += an;
    acc += ((unsigned)(pr_key[i] & 0xffffffffu) == (unsigned)(i >> 3)) ? 1.f : 0.f;
  }
  loss = wave_sum64(loss);
  sp = wave_sum64(sp);
  sn = wave_sum64(sn);
  acc = wave_sum64(acc);
  __shared__ float red[16][4];
  const int w = tid >> 6, l = tid & 63;
  if (l == 0) { red[w][0] = loss; red[w][1] = acc; red[w][2] = sp; red[w][3] = sn; }
  __syncthreads();
  if (tid == 0) {
    float L = 0, Ac = 0, Pm = 0, Nn = 0;
    for (int i = 0; i < 16; ++i) {
      L += red[i][0]; Ac += red[i][1]; Pm += red[i][2]; Nn += red[i][3];
    }
    out[0] = L / NTOT;   // W = 1.0
    out[1] = Ac / NTOT;
    out[2] = Pm / NTOT;
    out[3] = Nn / NTOT;
  }
}

extern "C" void kernel_launch(void* const* d_in, const int* in_sizes, int n_in,
                              void* d_out, int out_size, void* d_ws, size_t ws_size,
                              hipStream_t stream) {
  const float* inputs = (const float*)d_in[0];
  float* out = (float*)d_out;
  char* w = (char*)d_ws;
  float* sq  = (float*)(w);                                        // 32 KB
  float* psq = (float*)(w + 32768);                                // 4 KB
  unsigned long long* an_key = (unsigned long long*)(w + 36864);   // 64 KB
  unsigned long long* ap_key = (unsigned long long*)(w + 102400);  // 64 KB
  unsigned long long* pr_key = (unsigned long long*)(w + 167936);  // 64 KB
  __hip_bfloat16* A16 = (__hip_bfloat16*)(w + 233472);             // 8 MB
  __hip_bfloat16* P16 = (__hip_bfloat16*)(w + 233472 + (size_t)NTOT * DIM * 2);

  prep<<<NTOT + NWAYS, 64, 0, stream>>>(inputs, sq, psq, A16, P16,
                                        an_key, ap_key, pr_key);
  gemm_fused<<<NSYM + 512, 256, 0, stream>>>(A16, P16, sq, psq,
                                             an_key, ap_key, pr_key);
  finalize_kernel<<<1, 1024, 0, stream>>>(sq, an_key, ap_key, pr_key, out);
}

// Round 3
// 163.172 us; speedup vs baseline: 1.5855x; 1.1093x over previous
//
#include <hip/hip_runtime.h>
#include <hip/hip_bf16.h>
#include <stdint.h>

#define NTOT  8192
#define DIM   512
#define NI    8
#define NWAYS 1024
#define TILE  128
#define BK    64
#define NSYM  2080   /* 64*65/2 upper-triangle tile pairs */
#define MARGINV 0.3f

typedef __bf16 bf16x8 __attribute__((ext_vector_type(8)));
typedef float  f32x4  __attribute__((ext_vector_type(4)));

// order-preserving float<->uint map (monotonic for all finite floats +/- inf)
__device__ __forceinline__ unsigned f2o(float f) {
  unsigned u = __float_as_uint(f);
  return (u & 0x80000000u) ? ~u : (u | 0x80000000u);
}
__device__ __forceinline__ float o2f(unsigned u) {
  u = (u & 0x80000000u) ? (u & 0x7fffffffu) : ~u;
  return __uint_as_float(u);
}

__device__ __forceinline__ float wave_sum64(float v) {
#pragma unroll
  for (int s = 32; s; s >>= 1) v += __shfl_xor(v, s, 64);
  return v;
}

__device__ __forceinline__ void async_ld16(const void* g, void* l) {
  __builtin_amdgcn_global_load_lds(
      (__attribute__((address_space(1))) void*)(uintptr_t)g,
      (__attribute__((address_space(3))) void*)l, 16, 0, 0);
}

// ---- prep: 4 waves/block, one row (or proto) per wave, float4 loads ----
__global__ __launch_bounds__(256) void prep(
    const float* __restrict__ A, float* __restrict__ sq,
    float* __restrict__ psq, __hip_bfloat16* __restrict__ A16,
    __hip_bfloat16* __restrict__ P16,
    unsigned long long* __restrict__ an_key,
    unsigned long long* __restrict__ ap_key,
    unsigned long long* __restrict__ pr_key) {
  const int w = threadIdx.x >> 6;
  const int l = threadIdx.x & 63;
  const int b = blockIdx.x;
  if (b < NTOT / 4) {
    const int row = b * 4 + w;
    const float4* rp = (const float4*)(A + (size_t)row * DIM);
    ushort4* op = (ushort4*)(A16 + (size_t)row * DIM);
    float s = 0.f;
#pragma unroll
    for (int m = 0; m < 2; ++m) {
      const float4 v = rp[l + 64 * m];
      s = fmaf(v.x, v.x, fmaf(v.y, v.y, fmaf(v.z, v.z, fmaf(v.w, v.w, s))));
      ushort4 o;
      __hip_bfloat16 h;
      h = __float2bfloat16(v.x); o.x = *(unsigned short*)&h;
      h = __float2bfloat16(v.y); o.y = *(unsigned short*)&h;
      h = __float2bfloat16(v.z); o.z = *(unsigned short*)&h;
      h = __float2bfloat16(v.w); o.w = *(unsigned short*)&h;
      op[l + 64 * m] = o;
    }
    s = wave_sum64(s);
    if (l == 0) {
      sq[row] = s;
      an_key[row] = ~0ull;
      pr_key[row] = ~0ull;
      ap_key[row] = 0ull;
    }
  } else {
    const int c = (b - NTOT / 4) * 4 + w;  // proto id
    ushort4* op = (ushort4*)(P16 + (size_t)c * DIM);
    float s = 0.f;
#pragma unroll
    for (int m = 0; m < 2; ++m) {
      float4 p = {0.f, 0.f, 0.f, 0.f};
#pragma unroll
      for (int r = 0; r < NI; ++r) {
        const float4 v =
            ((const float4*)(A + (size_t)(c * NI + r) * DIM))[l + 64 * m];
        p.x += v.x; p.y += v.y; p.z += v.z; p.w += v.w;
      }
      p.x *= (1.f / NI); p.y *= (1.f / NI); p.z *= (1.f / NI); p.w *= (1.f / NI);
      s = fmaf(p.x, p.x, fmaf(p.y, p.y, fmaf(p.z, p.z, fmaf(p.w, p.w, s))));
      ushort4 o;
      __hip_bfloat16 h;
      h = __float2bfloat16(p.x); o.x = *(unsigned short*)&h;
      h = __float2bfloat16(p.y); o.y = *(unsigned short*)&h;
      h = __float2bfloat16(p.z); o.z = *(unsigned short*)&h;
      h = __float2bfloat16(p.w); o.w = *(unsigned short*)&h;
      op[l + 64 * m] = o;
    }
    s = wave_sum64(s);
    if (l == 0) psq[c] = s;
  }
}

// ---- fused symmetric GEMM + min/argmin/max epilogues ----
// blocks [0,NSYM): upper-triangle tile pairs, remapped into 8x8-tile
// supertiles so a window of 64 consecutive block IDs touches <=2 MB (L2).
// blocks [NSYM, NSYM+512): inputs x protos -> pr_key argmin.
__global__ __launch_bounds__(256) void gemm_fused(
    const __hip_bfloat16* __restrict__ A, const __hip_bfloat16* __restrict__ P,
    const float* __restrict__ sq, const float* __restrict__ psq,
    unsigned long long* __restrict__ an_key,
    unsigned long long* __restrict__ ap_key,
    unsigned long long* __restrict__ pr_key) {
  __shared__ __align__(16) __hip_bfloat16 As[2][TILE * BK];  // 2 x 16 KB
  __shared__ __align__(16) __hip_bfloat16 Bs[2][TILE * BK];  // 2 x 16 KB
  __shared__ unsigned long long rowkey[TILE][2];
  __shared__ unsigned long long sidekey[TILE][2];

  const int b = blockIdx.x;
  const bool isProto = b >= NSYM;
  int bi, bj;
  const __hip_bfloat16* Bmat;
  const float* sqB;
  if (!isProto) {
    // supertile decode: pairs (Si<=Sj) of 8x8-tile supertiles; diag has 36
    // tile pairs, offdiag 64.
    int rem = b, Si = 0, Sj = 0;
    for (;;) {
      const int cnt = (Si == Sj) ? 36 : 64;
      if (rem < cnt) break;
      rem -= cnt;
      ++Si;
      if (Si > Sj) { Si = 0; ++Sj; }
    }
    int bi_l, bj_l;
    if (Si == Sj) {
      bj_l = 0;
      while ((bj_l + 1) * (bj_l + 2) / 2 <= rem) ++bj_l;
      bi_l = rem - bj_l * (bj_l + 1) / 2;
    } else {
      bi_l = rem & 7;
      bj_l = rem >> 3;
    }
    bi = Si * 8 + bi_l;
    bj = Sj * 8 + bj_l;
    Bmat = A;
    sqB = sq;
  } else {
    const int p = b - NSYM;
    bj = p & 7;
    bi = p >> 3;
    Bmat = P;
    sqB = psq;
  }
  const int rowBase = bi * TILE;
  const int colBase = bj * TILE;
  const bool isDiag = !isProto && (bi == bj);
  const bool colSide = !isProto && (bi != bj);

  const int t = threadIdx.x;
  const int lane = t & 63;
  const int wv = t >> 6;
  const int wr = wv >> 1;
  const int wc = wv & 1;
  const int quad = lane >> 4;
  const int lc = lane & 15;
  const int sw = lc & 7;  // xor-swizzle key for fragment reads (= row&7)

  const int srow = t >> 3;                         // staging row in 32-chunk
  const int ssw = ((t & 7) ^ ((t >> 3) & 7)) * 8;  // swizzled source col

  const __hip_bfloat16* gA = A + (size_t)(rowBase + srow) * DIM + ssw;
  const __hip_bfloat16* gB = Bmat + (size_t)(colBase + srow) * DIM + ssw;

  f32x4 acc[4][4] = {};

  // prologue: stage K-tile 0 into buffer 0
#pragma unroll
  for (int it = 0; it < 4; ++it) {
    async_ld16(gA + (size_t)it * 32 * DIM, (char*)(&As[0][0]) + it * 4096 + wv * 1024);
    async_ld16(gB + (size_t)it * 32 * DIM, (char*)(&Bs[0][0]) + it * 4096 + wv * 1024);
  }
  __syncthreads();

  int cur = 0;
  for (int kt = 0; kt < DIM; kt += BK) {
    const int nxt = cur ^ 1;
    if (kt + BK < DIM) {  // issue-ahead: next K-tile overlaps this compute
#pragma unroll
      for (int it = 0; it < 4; ++it) {
        async_ld16(gA + (size_t)it * 32 * DIM + kt + BK,
                   (char*)(&As[nxt][0]) + it * 4096 + wv * 1024);
        async_ld16(gB + (size_t)it * 32 * DIM + kt + BK,
                   (char*)(&Bs[nxt][0]) + it * 4096 + wv * 1024);
      }
    }
#pragma unroll
    for (int kk = 0; kk < BK; kk += 32) {
      bf16x8 af[4], bfr[4];
#pragma unroll
      for (int x = 0; x < 4; ++x) {
        af[x]  = *(const bf16x8*)(&As[cur][0] + (wr * 64 + x * 16 + lc) * BK +
                                  (((kk >> 3) + quad) ^ sw) * 8);
        bfr[x] = *(const bf16x8*)(&Bs[cur][0] + (wc * 64 + x * 16 + lc) * BK +
                                  (((kk >> 3) + quad) ^ sw) * 8);
      }
#pragma unroll
      for (int x = 0; x < 4; ++x)
#pragma unroll
        for (int y = 0; y < 4; ++y)
          acc[x][y] = __builtin_amdgcn_mfma_f32_16x16x32_bf16(af[x], bfr[y],
                                                              acc[x][y], 0, 0, 0);
    }
    __syncthreads();  // publishes buf[nxt]; all reads of buf[cur] done
    cur = nxt;
  }

  // ---- epilogue. C/D layout: col=lane&15, row=quad*4+reg ----
  float sb[4];
#pragma unroll
  for (int y = 0; y < 4; ++y) sb[y] = sqB[colBase + wc * 64 + y * 16 + lc];

  const float INF = __int_as_float(0x7f800000);

#pragma unroll
  for (int x = 0; x < 4; ++x) {
    unsigned long long kmin[4] = {~0ull, ~0ull, ~0ull, ~0ull};
    unsigned long long kmax[4] = {0ull, 0ull, 0ull, 0ull};
#pragma unroll
    for (int y = 0; y < 4; ++y) {
      const int col = colBase + wc * 64 + y * 16 + lc;
#pragma unroll
      for (int r = 0; r < 4; ++r) {
        const float v = fmaf(-2.f, acc[x][y][r], sb[y]);
        if (isDiag) {
          const int row = rowBase + wr * 64 + x * 16 + quad * 4 + r;
          const bool same = (row >> 3) == (col >> 3);
          const unsigned long long kn =
              ((unsigned long long)f2o(same ? INF : v) << 32) | (unsigned)col;
          const unsigned long long kx =
              ((unsigned long long)f2o(same ? v : -INF) << 32) | (unsigned)col;
          if (kn < kmin[r]) kmin[r] = kn;
          if (kx > kmax[r]) kmax[r] = kx;
        } else {
          const unsigned long long kn =
              ((unsigned long long)f2o(v) << 32) | (unsigned)col;
          if (kn < kmin[r]) kmin[r] = kn;
        }
      }
    }
#pragma unroll
    for (int r = 0; r < 4; ++r) {
#pragma unroll
      for (int s = 1; s < 16; s <<= 1) {
        const unsigned long long o = __shfl_xor(kmin[r], s, 64);
        if (o < kmin[r]) kmin[r] = o;
      }
    }
    if (isDiag) {
#pragma unroll
      for (int r = 0; r < 4; ++r) {
#pragma unroll
        for (int s = 1; s < 16; s <<= 1) {
          const unsigned long long o = __shfl_xor(kmax[r], s, 64);
          if (o > kmax[r]) kmax[r] = o;
        }
      }
    }
    if (lc == 0) {
#pragma unroll
      for (int r = 0; r < 4; ++r) {
        rowkey[wr * 64 + x * 16 + quad * 4 + r][wc] = kmin[r];
        if (isDiag) sidekey[wr * 64 + x * 16 + quad * 4 + r][wc] = kmax[r];
      }
    }
  }

  // col-side min (off-diagonal sym blocks): transpose direction
  if (colSide) {
    float sa[4][4];
#pragma unroll
    for (int x = 0; x < 4; ++x)
#pragma unroll
      for (int r = 0; r < 4; ++r)
        sa[x][r] = sq[rowBase + wr * 64 + x * 16 + quad * 4 + r];
#pragma unroll
    for (int y = 0; y < 4; ++y) {
      unsigned long long kc = ~0ull;
#pragma unroll
      for (int x = 0; x < 4; ++x)
#pragma unroll
        for (int r = 0; r < 4; ++r) {
          const int row = rowBase + wr * 64 + x * 16 + quad * 4 + r;
          const float v = fmaf(-2.f, acc[x][y][r], sa[x][r]);
          const unsigned long long k =
              ((unsigned long long)f2o(v) << 32) | (unsigned)row;
          if (k < kc) kc = k;
        }
#pragma unroll
      for (int s = 16; s < 64; s <<= 1) {
        const unsigned long long o = __shfl_xor(kc, s, 64);
        if (o < kc) kc = o;
      }
      if (quad == 0) sidekey[wc * 64 + y * 16 + lc][wr] = kc;
    }
  }

  __syncthreads();
  if (t < TILE) {
    unsigned long long a = rowkey[t][0];
    const unsigned long long c = rowkey[t][1];
    if (c < a) a = c;
    atomicMin((isProto ? pr_key : an_key) + rowBase + t, a);
  } else if (t < 2 * TILE) {
    const int i = t - TILE;
    if (colSide) {
      unsigned long long a = sidekey[i][0];
      const unsigned long long c = sidekey[i][1];
      if (c < a) a = c;
      atomicMin(an_key + colBase + i, a);
    } else if (isDiag) {
      unsigned long long a = sidekey[i][0];
      const unsigned long long c = sidekey[i][1];
      if (c > a) a = c;
      atomicMax(ap_key + rowBase + i, a);
    }
  }
}

// ---- final scalar reductions ----
__global__ void finalize_kernel(const float* __restrict__ sq,
                                const unsigned long long* __restrict__ an_key,
                                const unsigned long long* __restrict__ ap_key,
                                const unsigned long long* __restrict__ pr_key,
                                float* __restrict__ out) {
  const int tid = threadIdx.x;  // 1024 threads
  float loss = 0.f, sp = 0.f, sn = 0.f, acc = 0.f;
  for (int i = tid; i < NTOT; i += 1024) {
    const float s = sq[i];
    const float ap = sqrtf(fmaxf(s + o2f((unsigned)(ap_key[i] >> 32)), 1e-12f));
    const float an = sqrtf(fmaxf(s + o2f((unsigned)(an_key[i] >> 32)), 1e-12f));
    loss += fmaxf(ap - an + MARGINV, 0.f);
    sp += ap;
    sn += an;
    acc += ((unsigned)(pr_key[i] & 0xffffffffu) == (unsigned)(i >> 3)) ? 1.f : 0.f;
  }
  loss = wave_sum64(loss);
  sp = wave_sum64(sp);
  sn = wave_sum64(sn);
  acc = wave_sum64(acc);
  __shared__ float red[16][4];
  const int w = tid >> 6, l = tid & 63;
  if (l == 0) { red[w][0] = loss; red[w][1] = acc; red[w][2] = sp; red[w][3] = sn; }
  __syncthreads();
  if (tid == 0) {
    float L = 0, Ac = 0, Pm = 0, Nn = 0;
    for (int i = 0; i < 16; ++i) {
      L += red[i][0]; Ac += red[i][1]; Pm += red[i][2]; Nn += red[i][3];
    }
    out[0] = L / NTOT;   // W = 1.0
    out[1] = Ac / NTOT;
    out[2] = Pm / NTOT;
    out[3] = Nn / NTOT;
  }
}

extern "C" void kernel_launch(void* const* d_in, const int* in_sizes, int n_in,
                              void* d_out, int out_size, void* d_ws, size_t ws_size,
                              hipStream_t stream) {
  const float* inputs = (const float*)d_in[0];
  float* out = (float*)d_out;
  char* w = (char*)d_ws;
  float* sq  = (float*)(w);                                        // 32 KB
  float* psq = (float*)(w + 32768);                                // 4 KB
  unsigned long long* an_key = (unsigned long long*)(w + 36864);   // 64 KB
  unsigned long long* ap_key = (unsigned long long*)(w + 102400);  // 64 KB
  unsigned long long* pr_key = (unsigned long long*)(w + 167936);  // 64 KB
  __hip_bfloat16* A16 = (__hip_bfloat16*)(w + 233472);             // 8 MB
  __hip_bfloat16* P16 = (__hip_bfloat16*)(w + 233472 + (size_t)NTOT * DIM * 2);

  prep<<<NTOT / 4 + NWAYS / 4, 256, 0, stream>>>(inputs, sq, psq, A16, P16,
                                                 an_key, ap_key, pr_key);
  gemm_fused<<<NSYM + 512, 256, 0, stream>>>(A16, P16, sq, psq,
                                             an_key, ap_key, pr_key);
  finalize_kernel<<<1, 1024, 0, stream>>>(sq, an_key, ap_key, pr_key, out);
}

// Round 4
// 161.210 us; speedup vs baseline: 1.6048x; 1.0122x over previous
//
#include <hip/hip_runtime.h>
#include <hip/hip_bf16.h>
#include <stdint.h>

#define NTOT  8192
#define DIM   512
#define NI    8
#define NWAYS 1024
#define TILE  128
#define BK    64
#define NSYM  2080   /* 64*65/2 upper-triangle tile pairs */
#define NBLK  2592   /* NSYM + 512 proto blocks = 8 * 324 */
#define MARGINV 0.3f

typedef float f32x4 __attribute__((ext_vector_type(4)));

// order-preserving float<->uint map (monotonic for all finite floats +/- inf)
__device__ __forceinline__ unsigned f2o(float f) {
  unsigned u = __float_as_uint(f);
  return (u & 0x80000000u) ? ~u : (u | 0x80000000u);
}
__device__ __forceinline__ float o2f(unsigned u) {
  u = (u & 0x80000000u) ? (u & 0x7fffffffu) : ~u;
  return __uint_as_float(u);
}

__device__ __forceinline__ float wave_sum64(float v) {
#pragma unroll
  for (int s = 32; s; s >>= 1) v += __shfl_xor(v, s, 64);
  return v;
}

__device__ __forceinline__ void async_ld16(const void* g, void* l) {
  __builtin_amdgcn_global_load_lds(
      (__attribute__((address_space(1))) void*)(uintptr_t)g,
      (__attribute__((address_space(3))) void*)l, 16, 0, 0);
}

// ---- prep: sq-norms + fp8(e4m3) cast + key init; protos in tail blocks ----
__global__ __launch_bounds__(256) void prep(
    const float* __restrict__ A, float* __restrict__ sq,
    float* __restrict__ psq, unsigned char* __restrict__ A8,
    unsigned char* __restrict__ P8,
    unsigned long long* __restrict__ an_key,
    unsigned long long* __restrict__ ap_key,
    unsigned long long* __restrict__ pr_key) {
  const int w = threadIdx.x >> 6;
  const int l = threadIdx.x & 63;
  const int b = blockIdx.x;
  if (b < NTOT / 4) {
    const int row = b * 4 + w;
    const float4* rp = (const float4*)(A + (size_t)row * DIM);
    unsigned* op = (unsigned*)(A8 + (size_t)row * DIM);
    float s = 0.f;
#pragma unroll
    for (int m = 0; m < 2; ++m) {
      const float4 v = rp[l + 64 * m];
      s = fmaf(v.x, v.x, fmaf(v.y, v.y, fmaf(v.z, v.z, fmaf(v.w, v.w, s))));
      int wd = 0;
      wd = __builtin_amdgcn_cvt_pk_fp8_f32(v.x, v.y, wd, false);
      wd = __builtin_amdgcn_cvt_pk_fp8_f32(v.z, v.w, wd, true);
      op[l + 64 * m] = (unsigned)wd;
    }
    s = wave_sum64(s);
    if (l == 0) {
      sq[row] = s;
      an_key[row] = ~0ull;
      pr_key[row] = ~0ull;
      ap_key[row] = 0ull;
    }
  } else {
    const int c = (b - NTOT / 4) * 4 + w;  // proto id
    unsigned* op = (unsigned*)(P8 + (size_t)c * DIM);
    float s = 0.f;
#pragma unroll
    for (int m = 0; m < 2; ++m) {
      float4 p = {0.f, 0.f, 0.f, 0.f};
#pragma unroll
      for (int r = 0; r < NI; ++r) {
        const float4 v =
            ((const float4*)(A + (size_t)(c * NI + r) * DIM))[l + 64 * m];
        p.x += v.x; p.y += v.y; p.z += v.z; p.w += v.w;
      }
      p.x *= (1.f / NI); p.y *= (1.f / NI); p.z *= (1.f / NI); p.w *= (1.f / NI);
      s = fmaf(p.x, p.x, fmaf(p.y, p.y, fmaf(p.z, p.z, fmaf(p.w, p.w, s))));
      int wd = 0;
      wd = __builtin_amdgcn_cvt_pk_fp8_f32(p.x, p.y, wd, false);
      wd = __builtin_amdgcn_cvt_pk_fp8_f32(p.z, p.w, wd, true);
      op[l + 64 * m] = (unsigned)wd;
    }
    s = wave_sum64(s);
    if (l == 0) psq[c] = s;
  }
}

// ---- fused symmetric fp8 GEMM + min/argmin/max epilogues ----
// Block id remapped XCD-contiguous: id = (b&7)*324 + (b>>3), so each XCD's
// concurrent window is ~64 consecutive logical ids ~= one 8x8-tile supertile
// (~1-2 MB -> L2-resident). logical [0,NSYM): upper triangle; rest: protos.
__global__ __launch_bounds__(256) void gemm_fused(
    const unsigned char* __restrict__ A, const unsigned char* __restrict__ P,
    const float* __restrict__ sq, const float* __restrict__ psq,
    unsigned long long* __restrict__ an_key,
    unsigned long long* __restrict__ ap_key,
    unsigned long long* __restrict__ pr_key) {
  __shared__ __align__(16) unsigned char As[2][TILE * BK];  // 2 x 8 KB
  __shared__ __align__(16) unsigned char Bs[2][TILE * BK];  // 2 x 8 KB
  __shared__ unsigned long long rowkey[TILE][2];
  __shared__ unsigned long long sidekey[TILE][2];

  const int braw = blockIdx.x;
  const int b = (braw & 7) * (NBLK / 8) + (braw >> 3);  // XCD-contiguous
  const bool isProto = b >= NSYM;
  int bi, bj;
  const unsigned char* Bmat;
  const float* sqB;
  if (!isProto) {
    // supertile decode: pairs (Si<=Sj) of 8x8-tile supertiles
    int rem = b, Si = 0, Sj = 0;
    for (;;) {
      const int cnt = (Si == Sj) ? 36 : 64;
      if (rem < cnt) break;
      rem -= cnt;
      ++Si;
      if (Si > Sj) { Si = 0; ++Sj; }
    }
    int bi_l, bj_l;
    if (Si == Sj) {
      bj_l = 0;
      while ((bj_l + 1) * (bj_l + 2) / 2 <= rem) ++bj_l;
      bi_l = rem - bj_l * (bj_l + 1) / 2;
    } else {
      bi_l = rem & 7;
      bj_l = rem >> 3;
    }
    bi = Si * 8 + bi_l;
    bj = Sj * 8 + bj_l;
    Bmat = A;
    sqB = sq;
  } else {
    const int p = b - NSYM;
    bj = p & 7;
    bi = p >> 3;
    Bmat = P;
    sqB = psq;
  }
  const int rowBase = bi * TILE;
  const int colBase = bj * TILE;
  const bool isDiag = !isProto && (bi == bj);
  const bool colSide = !isProto && (bi != bj);

  const int t = threadIdx.x;
  const int lane = t & 63;
  const int wv = t >> 6;
  const int wr = wv >> 1;
  const int wc = wv & 1;
  const int quad = lane >> 4;
  const int lc = lane & 15;
  // fragment-read swizzle: s(row) depends only on lc (row mod 16)
  const int s_lc = (lc & 3) ^ ((lc >> 2) & 3);
  const int koff0 = (((quad >> 1) ^ s_lc) * 16) + (quad & 1) * 8;       // kk=0
  const int koff1 = (((2 + (quad >> 1)) ^ s_lc) * 16) + (quad & 1) * 8; // kk=1

  // staging: lane covers row wv*16+(lane>>2) of a 64-row round, 16B unit
  const int strow = wv * 16 + (lane >> 2);
  const int s_st = ((lane >> 2) & 3) ^ ((lane >> 4) & 3);
  const int ucol = ((lane & 3) ^ s_st) * 16;
  const unsigned char* gA = A + (size_t)(rowBase + strow) * DIM + ucol;
  const unsigned char* gB = Bmat + (size_t)(colBase + strow) * DIM + ucol;
  const int ldsOff = wv * 1024 + lane * 16;

  f32x4 acc[4][4] = {};

  // prologue: stage K-tile 0 into buffer 0 (2 rounds x 64 rows per matrix)
#pragma unroll
  for (int rd = 0; rd < 2; ++rd) {
    async_ld16(gA + rd * 32768, &As[0][rd * 4096 + ldsOff]);
    async_ld16(gB + rd * 32768, &Bs[0][rd * 4096 + ldsOff]);
  }
  __syncthreads();

  int rowA[4], rowB[4];
#pragma unroll
  for (int x = 0; x < 4; ++x) {
    rowA[x] = (wr * 64 + x * 16 + lc) * BK;
    rowB[x] = (wc * 64 + x * 16 + lc) * BK;
  }

  int cur = 0;
  for (int kt = 0; kt < DIM; kt += BK) {
    const int nxt = cur ^ 1;
    if (kt + BK < DIM) {  // issue-ahead next K-tile
#pragma unroll
      for (int rd = 0; rd < 2; ++rd) {
        async_ld16(gA + rd * 32768 + kt + BK, &As[nxt][rd * 4096 + ldsOff]);
        async_ld16(gB + rd * 32768 + kt + BK, &Bs[nxt][rd * 4096 + ldsOff]);
      }
    }
#pragma unroll
    for (int kk = 0; kk < 2; ++kk) {
      const int ko = kk ? koff1 : koff0;
      long af[4], bfr[4];
#pragma unroll
      for (int x = 0; x < 4; ++x) {
        af[x]  = *(const long*)(&As[cur][rowA[x] + ko]);
        bfr[x] = *(const long*)(&Bs[cur][rowB[x] + ko]);
      }
#pragma unroll
      for (int x = 0; x < 4; ++x)
#pragma unroll
        for (int y = 0; y < 4; ++y)
          acc[x][y] = __builtin_amdgcn_mfma_f32_16x16x32_fp8_fp8(
              af[x], bfr[y], acc[x][y], 0, 0, 0);
    }
    __syncthreads();  // publishes buf[nxt]; all reads of buf[cur] done
    cur = nxt;
  }

  // ---- epilogue. C/D layout: col=lane&15, row=quad*4+reg ----
  float sb[4];
#pragma unroll
  for (int y = 0; y < 4; ++y) sb[y] = sqB[colBase + wc * 64 + y * 16 + lc];

  const float INF = __int_as_float(0x7f800000);

#pragma unroll
  for (int x = 0; x < 4; ++x) {
    unsigned long long kmin[4] = {~0ull, ~0ull, ~0ull, ~0ull};
    unsigned long long kmax[4] = {0ull, 0ull, 0ull, 0ull};
#pragma unroll
    for (int y = 0; y < 4; ++y) {
      const int col = colBase + wc * 64 + y * 16 + lc;
#pragma unroll
      for (int r = 0; r < 4; ++r) {
        const float v = fmaf(-2.f, acc[x][y][r], sb[y]);
        if (isDiag) {
          const int row = rowBase + wr * 64 + x * 16 + quad * 4 + r;
          const bool same = (row >> 3) == (col >> 3);
          const unsigned long long kn =
              ((unsigned long long)f2o(same ? INF : v) << 32) | (unsigned)col;
          const unsigned long long kx =
              ((unsigned long long)f2o(same ? v : -INF) << 32) | (unsigned)col;
          if (kn < kmin[r]) kmin[r] = kn;
          if (kx > kmax[r]) kmax[r] = kx;
        } else {
          const unsigned long long kn =
              ((unsigned long long)f2o(v) << 32) | (unsigned)col;
          if (kn < kmin[r]) kmin[r] = kn;
        }
      }
    }
#pragma unroll
    for (int r = 0; r < 4; ++r) {
#pragma unroll
      for (int s = 1; s < 16; s <<= 1) {
        const unsigned long long o = __shfl_xor(kmin[r], s, 64);
        if (o < kmin[r]) kmin[r] = o;
      }
    }
    if (isDiag) {
#pragma unroll
      for (int r = 0; r < 4; ++r) {
#pragma unroll
        for (int s = 1; s < 16; s <<= 1) {
          const unsigned long long o = __shfl_xor(kmax[r], s, 64);
          if (o > kmax[r]) kmax[r] = o;
        }
      }
    }
    if (lc == 0) {
#pragma unroll
      for (int r = 0; r < 4; ++r) {
        rowkey[wr * 64 + x * 16 + quad * 4 + r][wc] = kmin[r];
        if (isDiag) sidekey[wr * 64 + x * 16 + quad * 4 + r][wc] = kmax[r];
      }
    }
  }

  // col-side min (off-diagonal sym blocks): transpose direction
  if (colSide) {
    float sa[4][4];
#pragma unroll
    for (int x = 0; x < 4; ++x)
#pragma unroll
      for (int r = 0; r < 4; ++r)
        sa[x][r] = sq[rowBase + wr * 64 + x * 16 + quad * 4 + r];
#pragma unroll
    for (int y = 0; y < 4; ++y) {
      unsigned long long kc = ~0ull;
#pragma unroll
      for (int x = 0; x < 4; ++x)
#pragma unroll
        for (int r = 0; r < 4; ++r) {
          const int row = rowBase + wr * 64 + x * 16 + quad * 4 + r;
          const float v = fmaf(-2.f, acc[x][y][r], sa[x][r]);
          const unsigned long long k =
              ((unsigned long long)f2o(v) << 32) | (unsigned)row;
          if (k < kc) kc = k;
        }
#pragma unroll
      for (int s = 16; s < 64; s <<= 1) {
        const unsigned long long o = __shfl_xor(kc, s, 64);
        if (o < kc) kc = o;
      }
      if (quad == 0) sidekey[wc * 64 + y * 16 + lc][wr] = kc;
    }
  }

  __syncthreads();
  if (t < TILE) {
    unsigned long long a = rowkey[t][0];
    const unsigned long long c = rowkey[t][1];
    if (c < a) a = c;
    atomicMin((isProto ? pr_key : an_key) + rowBase + t, a);
  } else if (t < 2 * TILE) {
    const int i = t - TILE;
    if (colSide) {
      unsigned long long a = sidekey[i][0];
      const unsigned long long c = sidekey[i][1];
      if (c < a) a = c;
      atomicMin(an_key + colBase + i, a);
    } else if (isDiag) {
      unsigned long long a = sidekey[i][0];
      const unsigned long long c = sidekey[i][1];
      if (c > a) a = c;
      atomicMax(ap_key + rowBase + i, a);
    }
  }
}

// ---- final scalar reductions ----
__global__ void finalize_kernel(const float* __restrict__ sq,
                                const unsigned long long* __restrict__ an_key,
                                const unsigned long long* __restrict__ ap_key,
                                const unsigned long long* __restrict__ pr_key,
                                float* __restrict__ out) {
  const int tid = threadIdx.x;  // 1024 threads
  float loss = 0.f, sp = 0.f, sn = 0.f, acc = 0.f;
#pragma unroll
  for (int i = tid; i < NTOT; i += 1024) {
    const float s = sq[i];
    const float ap = sqrtf(fmaxf(s + o2f((unsigned)(ap_key[i] >> 32)), 1e-12f));
    const float an = sqrtf(fmaxf(s + o2f((unsigned)(an_key[i] >> 32)), 1e-12f));
    loss += fmaxf(ap - an + MARGINV, 0.f);
    sp += ap;
    sn += an;
    acc += ((unsigned)(pr_key[i] & 0xffffffffu) == (unsigned)(i >> 3)) ? 1.f : 0.f;
  }
  loss = wave_sum64(loss);
  sp = wave_sum64(sp);
  sn = wave_sum64(sn);
  acc = wave_sum64(acc);
  __shared__ float red[16][4];
  const int w = tid >> 6, l = tid & 63;
  if (l == 0) { red[w][0] = loss; red[w][1] = acc; red[w][2] = sp; red[w][3] = sn; }
  __syncthreads();
  if (tid == 0) {
    float L = 0, Ac = 0, Pm = 0, Nn = 0;
    for (int i = 0; i < 16; ++i) {
      L += red[i][0]; Ac += red[i][1]; Pm += red[i][2]; Nn += red[i][3];
    }
    out[0] = L / NTOT;   // W = 1.0
    out[1] = Ac / NTOT;
    out[2] = Pm / NTOT;
    out[3] = Nn / NTOT;
  }
}

extern "C" void kernel_launch(void* const* d_in, const int* in_sizes, int n_in,
                              void* d_out, int out_size, void* d_ws, size_t ws_size,
                              hipStream_t stream) {
  const float* inputs = (const float*)d_in[0];
  float* out = (float*)d_out;
  char* w = (char*)d_ws;
  float* sq  = (float*)(w);                                        // 32 KB
  float* psq = (float*)(w + 32768);                                // 4 KB
  unsigned long long* an_key = (unsigned long long*)(w + 36864);   // 64 KB
  unsigned long long* ap_key = (unsigned long long*)(w + 102400);  // 64 KB
  unsigned long long* pr_key = (unsigned long long*)(w + 167936);  // 64 KB
  unsigned char* A8 = (unsigned char*)(w + 233472);                // 4 MB
  unsigned char* P8 = (unsigned char*)(w + 233472 + (size_t)NTOT * DIM);

  prep<<<NTOT / 4 + NWAYS / 4, 256, 0, stream>>>(inputs, sq, psq, A8, P8,
                                                 an_key, ap_key, pr_key);
  gemm_fused<<<NBLK, 256, 0, stream>>>(A8, P8, sq, psq,
                                       an_key, ap_key, pr_key);
  finalize_kernel<<<1, 1024, 0, stream>>>(sq, an_key, ap_key, pr_key, out);
}

// Round 5
// 135.014 us; speedup vs baseline: 1.9162x; 1.1940x over previous
//
#include <hip/hip_runtime.h>
#include <hip/hip_bf16.h>
#include <stdint.h>

#define NTOT  8192
#define DIM   512
#define NI    8
#define NWAYS 1024
#define TILE  128
#define BK    128
#define NSYM  2080   /* 64*65/2 upper-triangle tile pairs */
#define NBLK  2592   /* NSYM + 512 proto blocks = 8 * 324 */
#define MARGINV 0.3f

typedef float f32x4 __attribute__((ext_vector_type(4)));

// order-preserving float<->uint map (monotonic for all finite floats +/- inf)
__device__ __forceinline__ unsigned f2o(float f) {
  unsigned u = __float_as_uint(f);
  return (u & 0x80000000u) ? ~u : (u | 0x80000000u);
}
__device__ __forceinline__ float o2f(unsigned u) {
  u = (u & 0x80000000u) ? (u & 0x7fffffffu) : ~u;
  return __uint_as_float(u);
}

__device__ __forceinline__ float wave_sum64(float v) {
#pragma unroll
  for (int s = 32; s; s >>= 1) v += __shfl_xor(v, s, 64);
  return v;
}

__device__ __forceinline__ void async_ld16(const void* g, void* l) {
  __builtin_amdgcn_global_load_lds(
      (__attribute__((address_space(1))) void*)(uintptr_t)g,
      (__attribute__((address_space(3))) void*)l, 16, 0, 0);
}

// ---- prep: sq-norms + fp8(e4m3) cast + accumulator init; protos in tail ----
__global__ __launch_bounds__(256) void prep(
    const float* __restrict__ A, float* __restrict__ sq,
    float* __restrict__ psq, unsigned char* __restrict__ A8,
    unsigned char* __restrict__ P8,
    unsigned* __restrict__ an_u32, unsigned* __restrict__ ap_u32,
    unsigned long long* __restrict__ pr_key) {
  const int w = threadIdx.x >> 6;
  const int l = threadIdx.x & 63;
  const int b = blockIdx.x;
  if (b < NTOT / 4) {
    const int row = b * 4 + w;
    const float4* rp = (const float4*)(A + (size_t)row * DIM);
    unsigned* op = (unsigned*)(A8 + (size_t)row * DIM);
    float s = 0.f;
#pragma unroll
    for (int m = 0; m < 2; ++m) {
      const float4 v = rp[l + 64 * m];
      s = fmaf(v.x, v.x, fmaf(v.y, v.y, fmaf(v.z, v.z, fmaf(v.w, v.w, s))));
      int wd = 0;
      wd = __builtin_amdgcn_cvt_pk_fp8_f32(v.x, v.y, wd, false);
      wd = __builtin_amdgcn_cvt_pk_fp8_f32(v.z, v.w, wd, true);
      op[l + 64 * m] = (unsigned)wd;
    }
    s = wave_sum64(s);
    if (l == 0) {
      sq[row] = s;
      an_u32[row] = ~0u;
      ap_u32[row] = 0u;
      pr_key[row] = ~0ull;
    }
  } else {
    const int c = (b - NTOT / 4) * 4 + w;  // proto id
    unsigned* op = (unsigned*)(P8 + (size_t)c * DIM);
    float s = 0.f;
#pragma unroll
    for (int m = 0; m < 2; ++m) {
      float4 p = {0.f, 0.f, 0.f, 0.f};
#pragma unroll
      for (int r = 0; r < NI; ++r) {
        const float4 v =
            ((const float4*)(A + (size_t)(c * NI + r) * DIM))[l + 64 * m];
        p.x += v.x; p.y += v.y; p.z += v.z; p.w += v.w;
      }
      p.x *= (1.f / NI); p.y *= (1.f / NI); p.z *= (1.f / NI); p.w *= (1.f / NI);
      s = fmaf(p.x, p.x, fmaf(p.y, p.y, fmaf(p.z, p.z, fmaf(p.w, p.w, s))));
      int wd = 0;
      wd = __builtin_amdgcn_cvt_pk_fp8_f32(p.x, p.y, wd, false);
      wd = __builtin_amdgcn_cvt_pk_fp8_f32(p.z, p.w, wd, true);
      op[l + 64 * m] = (unsigned)wd;
    }
    s = wave_sum64(s);
    if (l == 0) psq[c] = s;
  }
}

// ---- fused symmetric fp8 GEMM + min/max epilogues, BK=128 dbuf ----
// LDS layout: 128-B rows, 8x16-B units, unit u of row r stored at u^(r&7).
// Staging (global_load_lds) stays lane-linear in LDS; fragment ds_read_b64
// lands 2 lanes/bank per 32-lane phase (free). Swizzle is transparent: both
// A and B fragments recover identical logical k.
__global__ __launch_bounds__(256) void gemm_fused(
    const unsigned char* __restrict__ A, const unsigned char* __restrict__ P,
    const float* __restrict__ sq, const float* __restrict__ psq,
    unsigned* __restrict__ an_u32, unsigned* __restrict__ ap_u32,
    unsigned long long* __restrict__ pr_key) {
  __shared__ __align__(16) unsigned char As[2][TILE * BK];  // 2 x 16 KB
  __shared__ __align__(16) unsigned char Bs[2][TILE * BK];  // 2 x 16 KB
  __shared__ unsigned rmin[TILE];
  __shared__ unsigned cmin[TILE];
  __shared__ unsigned amax[TILE];
  __shared__ unsigned long long rowkey[TILE][2];  // proto path only

  const int braw = blockIdx.x;
  const int b = (braw & 7) * (NBLK / 8) + (braw >> 3);  // XCD-contiguous
  const bool isProto = b >= NSYM;
  int bi, bj;
  const unsigned char* Bmat;
  const float* sqB;
  if (!isProto) {
    // supertile decode: pairs (Si<=Sj) of 8x8-tile supertiles
    int rem = b, Si = 0, Sj = 0;
    for (;;) {
      const int cnt = (Si == Sj) ? 36 : 64;
      if (rem < cnt) break;
      rem -= cnt;
      ++Si;
      if (Si > Sj) { Si = 0; ++Sj; }
    }
    int bi_l, bj_l;
    if (Si == Sj) {
      bj_l = 0;
      while ((bj_l + 1) * (bj_l + 2) / 2 <= rem) ++bj_l;
      bi_l = rem - bj_l * (bj_l + 1) / 2;
    } else {
      bi_l = rem & 7;
      bj_l = rem >> 3;
    }
    bi = Si * 8 + bi_l;
    bj = Sj * 8 + bj_l;
    Bmat = A;
    sqB = sq;
  } else {
    const int p = b - NSYM;
    bj = p & 7;
    bi = p >> 3;
    Bmat = P;
    sqB = psq;
  }
  const int rowBase = bi * TILE;
  const int colBase = bj * TILE;
  const bool isDiag = !isProto && (bi == bj);
  const bool colSide = !isProto && (bi != bj);

  const int t = threadIdx.x;
  const int lane = t & 63;
  const int wv = t >> 6;
  const int wr = wv >> 1;
  const int wc = wv & 1;
  const int quad = lane >> 4;
  const int lc = lane & 15;

  if (t < TILE) { rmin[t] = ~0u; cmin[t] = ~0u; amax[t] = 0u; }

  // fragment-read unit offsets per 32-k chunk c: unit = (2c + quad/2) ^ (lc&7)
  int koff[4];
#pragma unroll
  for (int c = 0; c < 4; ++c)
    koff[c] = (((c * 2 + (quad >> 1)) ^ (lc & 7)) * 16) + (quad & 1) * 8;

  int rowA[4], rowB[4];
#pragma unroll
  for (int x = 0; x < 4; ++x) {
    rowA[x] = (wr * 64 + x * 16 + lc) * BK;
    rowB[x] = (wc * 64 + x * 16 + lc) * BK;
  }

  // staging: lane covers (row = rr*8 + lane/8, phys unit = lane&7);
  // logical source unit = (lane&7) ^ (row&7). Wave wv does rounds wv*4..wv*4+3.
  const int l8 = lane >> 3;
  const int ul = ((lane & 7) ^ (l8 & 7)) * 16;
  const unsigned char* gA = A + (size_t)(rowBase + l8) * DIM + ul;
  const unsigned char* gB = Bmat + (size_t)(colBase + l8) * DIM + ul;
  const int ldsL = lane * 16;

  f32x4 acc[4][4] = {};

  // prologue: stage K-tile 0 into buffer 0
#pragma unroll
  for (int j = 0; j < 4; ++j) {
    const int rr = wv * 4 + j;
    async_ld16(gA + (size_t)rr * 8 * DIM, &As[0][rr * 1024 + ldsL]);
    async_ld16(gB + (size_t)rr * 8 * DIM, &Bs[0][rr * 1024 + ldsL]);
  }
  __syncthreads();

#pragma unroll
  for (int it = 0; it < 4; ++it) {
    const int cur = it & 1;
    const int nxt = cur ^ 1;
    const int kt = it * BK;
    if (it < 3) {  // issue-ahead next K-tile
#pragma unroll
      for (int j = 0; j < 4; ++j) {
        const int rr = wv * 4 + j;
        async_ld16(gA + (size_t)rr * 8 * DIM + kt + BK, &As[nxt][rr * 1024 + ldsL]);
        async_ld16(gB + (size_t)rr * 8 * DIM + kt + BK, &Bs[nxt][rr * 1024 + ldsL]);
      }
    }
    const unsigned char* Ac = &As[cur][0];
    const unsigned char* Bc = &Bs[cur][0];
#pragma unroll
    for (int c = 0; c < 4; ++c) {
      long af[4], bfr[4];
#pragma unroll
      for (int x = 0; x < 4; ++x) {
        af[x]  = *(const long*)(Ac + rowA[x] + koff[c]);
        bfr[x] = *(const long*)(Bc + rowB[x] + koff[c]);
      }
#pragma unroll
      for (int x = 0; x < 4; ++x)
#pragma unroll
        for (int y = 0; y < 4; ++y)
          acc[x][y] = __builtin_amdgcn_mfma_f32_16x16x32_fp8_fp8(
              af[x], bfr[y], acc[x][y], 0, 0, 0);
    }
    __syncthreads();  // publishes buf[nxt]; all reads of buf[cur] done
  }

  // ---- epilogue. C/D layout: col=lane&15, row=quad*4+reg ----
  float sb[4];
#pragma unroll
  for (int y = 0; y < 4; ++y) sb[y] = sqB[colBase + wc * 64 + y * 16 + lc];

  const float INF = __int_as_float(0x7f800000);

  if (!isProto) {
    // row-side: per-lane min over y, then one LDS u32-min atomic per (x,r)
#pragma unroll
    for (int x = 0; x < 4; ++x) {
#pragma unroll
      for (int r = 0; r < 4; ++r) {
        const int row = rowBase + wr * 64 + x * 16 + quad * 4 + r;
        float mv = INF, mx = -INF;
#pragma unroll
        for (int y = 0; y < 4; ++y) {
          const float v = fmaf(-2.f, acc[x][y][r], sb[y]);
          if (isDiag) {
            const int col = colBase + wc * 64 + y * 16 + lc;
            const bool same = (row >> 3) == (col >> 3);
            mv = fminf(mv, same ? INF : v);
            mx = fmaxf(mx, same ? v : -INF);
          } else {
            mv = fminf(mv, v);
          }
        }
        atomicMin(&rmin[row - rowBase], f2o(mv));
        if (isDiag) atomicMax(&amax[row - rowBase], f2o(mx));
      }
    }
    // col-side (off-diag): per-lane min over (x,r) per y
    if (colSide) {
      float sa[4][4];
#pragma unroll
      for (int x = 0; x < 4; ++x)
#pragma unroll
        for (int r = 0; r < 4; ++r)
          sa[x][r] = sq[rowBase + wr * 64 + x * 16 + quad * 4 + r];
#pragma unroll
      for (int y = 0; y < 4; ++y) {
        float cv = INF;
#pragma unroll
        for (int x = 0; x < 4; ++x)
#pragma unroll
          for (int r = 0; r < 4; ++r)
            cv = fminf(cv, fmaf(-2.f, acc[x][y][r], sa[x][r]));
        atomicMin(&cmin[wc * 64 + y * 16 + lc], f2o(cv));
      }
    }
  } else {
    // proto path: need argmin index -> u64 keys + 16-lane butterfly
#pragma unroll
    for (int x = 0; x < 4; ++x) {
      unsigned long long kmin[4] = {~0ull, ~0ull, ~0ull, ~0ull};
#pragma unroll
      for (int y = 0; y < 4; ++y) {
        const int col = colBase + wc * 64 + y * 16 + lc;
#pragma unroll
        for (int r = 0; r < 4; ++r) {
          const float v = fmaf(-2.f, acc[x][y][r], sb[y]);
          const unsigned long long kn =
              ((unsigned long long)f2o(v) << 32) | (unsigned)col;
          if (kn < kmin[r]) kmin[r] = kn;
        }
      }
#pragma unroll
      for (int r = 0; r < 4; ++r) {
#pragma unroll
        for (int s = 1; s < 16; s <<= 1) {
          const unsigned long long o = __shfl_xor(kmin[r], s, 64);
          if (o < kmin[r]) kmin[r] = o;
        }
      }
      if (lc == 0) {
#pragma unroll
        for (int r = 0; r < 4; ++r)
          rowkey[wr * 64 + x * 16 + quad * 4 + r][wc] = kmin[r];
      }
    }
  }

  __syncthreads();
  if (isProto) {
    if (t < TILE) {
      unsigned long long a = rowkey[t][0];
      const unsigned long long c = rowkey[t][1];
      if (c < a) a = c;
      atomicMin(pr_key + rowBase + t, a);
    }
  } else {
    if (t < TILE) {
      atomicMin(an_u32 + rowBase + t, rmin[t]);
    } else if (t < 2 * TILE) {
      const int i = t - TILE;
      if (colSide) atomicMin(an_u32 + colBase + i, cmin[i]);
      else if (isDiag) atomicMax(ap_u32 + rowBase + i, amax[i]);
    }
  }
}

// ---- final scalar reductions ----
__global__ void finalize_kernel(const float* __restrict__ sq,
                                const unsigned* __restrict__ an_u32,
                                const unsigned* __restrict__ ap_u32,
                                const unsigned long long* __restrict__ pr_key,
                                float* __restrict__ out) {
  const int tid = threadIdx.x;  // 1024 threads
  float loss = 0.f, sp = 0.f, sn = 0.f, acc = 0.f;
#pragma unroll
  for (int i = tid; i < NTOT; i += 1024) {
    const float s = sq[i];
    const float ap = sqrtf(fmaxf(s + o2f(ap_u32[i]), 1e-12f));
    const float an = sqrtf(fmaxf(s + o2f(an_u32[i]), 1e-12f));
    loss += fmaxf(ap - an + MARGINV, 0.f);
    sp += ap;
    sn += an;
    acc += ((unsigned)(pr_key[i] & 0xffffffffu) == (unsigned)(i >> 3)) ? 1.f : 0.f;
  }
  loss = wave_sum64(loss);
  sp = wave_sum64(sp);
  sn = wave_sum64(sn);
  acc = wave_sum64(acc);
  __shared__ float red[16][4];
  const int w = tid >> 6, l = tid & 63;
  if (l == 0) { red[w][0] = loss; red[w][1] = acc; red[w][2] = sp; red[w][3] = sn; }
  __syncthreads();
  if (tid == 0) {
    float L = 0, Ac = 0, Pm = 0, Nn = 0;
    for (int i = 0; i < 16; ++i) {
      L += red[i][0]; Ac += red[i][1]; Pm += red[i][2]; Nn += red[i][3];
    }
    out[0] = L / NTOT;   // W = 1.0
    out[1] = Ac / NTOT;
    out[2] = Pm / NTOT;
    out[3] = Nn / NTOT;
  }
}

extern "C" void kernel_launch(void* const* d_in, const int* in_sizes, int n_in,
                              void* d_out, int out_size, void* d_ws, size_t ws_size,
                              hipStream_t stream) {
  const float* inputs = (const float*)d_in[0];
  float* out = (float*)d_out;
  char* w = (char*)d_ws;
  float* sq  = (float*)(w);                                       // 32 KB
  float* psq = (float*)(w + 32768);                               // 4 KB
  unsigned* an_u32 = (unsigned*)(w + 36864);                      // 32 KB
  unsigned* ap_u32 = (unsigned*)(w + 69632);                      // 32 KB
  unsigned long long* pr_key = (unsigned long long*)(w + 102400); // 64 KB
  unsigned char* A8 = (unsigned char*)(w + 167936);               // 4 MB
  unsigned char* P8 = (unsigned char*)(w + 167936 + (size_t)NTOT * DIM);

  prep<<<NTOT / 4 + NWAYS / 4, 256, 0, stream>>>(inputs, sq, psq, A8, P8,
                                                 an_u32, ap_u32, pr_key);
  gemm_fused<<<NBLK, 256, 0, stream>>>(A8, P8, sq, psq,
                                       an_u32, ap_u32, pr_key);
  finalize_kernel<<<1, 1024, 0, stream>>>(sq, an_u32, ap_u32, pr_key, out);
}